// Round 4
// baseline (92.903 us; speedup 1.0000x reference)
//
#include <hip/hip_runtime.h>
#include <math.h>

namespace {
constexpr int P = 4096, O = 32, H = 26, V = 48;
constexpr int SLOTS = 4;              // lanes cooperating per (p,o)
constexpr int PPB = 256 / SLOTS;      // points per block = 64
constexpr float EPSV = 1e-4f;         // strict < EPSV == numpy's (f32 <= 1e-4 f64)
}

// 4 lanes per (point p, object o): slot s covers faces {s, s+4, ...} and edges
// {s, s+4, ...}; shfl-butterfly merge with first-index tiebreaks reproduces
// numpy's argmax/argmin semantics exactly. Per-element arithmetic replicates
// numpy rounding: separate mul/add (no FMA), sequential 3-term sums, IEEE
// div/sqrt.
__global__ __launch_bounds__(256, 4) void zono_kernel(
    const float* __restrict__ point,   // [P][3]
    const float* __restrict__ hA,      // [O][H][3]
    const float* __restrict__ hb,      // [O][H]
    const float* __restrict__ v1g,     // [O][V][3]
    const float* __restrict__ v2g,     // [O][V][3]
    float* __restrict__ dist_out,      // [P][O]
    float* __restrict__ grad_out)      // [P][O][3]
{
    __shared__ float4 sAb[H];   // {a0,a1,a2,b}
    __shared__ float4 sV1[V];   // {v1_0,v1_1,v1_2,denom}
    __shared__ float4 sE[V];    // {e0,e1,e2,unused}

    const int o   = blockIdx.y;
    const int tid = threadIdx.x;

    if (tid < H) {
        const float* a = hA + (o * H + tid) * 3;
        sAb[tid] = make_float4(a[0], a[1], a[2], hb[o * H + tid]);
    } else if (tid >= 32 && tid < 32 + V) {
        const int v = tid - 32;
        const float* A1 = v1g + (o * V + v) * 3;
        const float* A2 = v2g + (o * V + v) * 3;
        const float x0 = A1[0], x1 = A1[1], x2 = A1[2];
        const float e0 = __fsub_rn(A2[0], x0);
        const float e1 = __fsub_rn(A2[1], x1);
        const float e2 = __fsub_rn(A2[2], x2);
        const float den = __fadd_rn(__fadd_rn(__fmul_rn(e0, e0), __fmul_rn(e1, e1)),
                                    __fmul_rn(e2, e2));
        sV1[v] = make_float4(x0, x1, x2, den);
        sE[v]  = make_float4(e0, e1, e2, 0.f);
    }
    __syncthreads();

    const int slot   = tid & (SLOTS - 1);
    const int p      = blockIdx.x * PPB + (tid >> 2);
    const float p0 = point[p * 3 + 0];
    const float p1 = point[p * 3 + 1];
    const float p2 = point[p * 3 + 2];

    // ---- face pass over this slot's faces ----
    bool  is_neg  = true;
    float maxv    = -INFINITY; int maxi = slot;
    float minperp =  INFINITY; int mini = slot;

    for (int h = slot; h < H; h += SLOTS) {
        const float4 ab = sAb[h];
        const float sh = __fsub_rn(
            __fadd_rn(__fadd_rn(__fmul_rn(p0, ab.x), __fmul_rn(p1, ab.y)),
                      __fmul_rn(p2, ab.z)),
            ab.w);
        if (sh > 0.f) is_neg = false;
        if (sh > maxv) { maxv = sh; maxi = h; }   // strict > == first argmax in-slot

        const float pp0 = __fsub_rn(p0, __fmul_rn(sh, ab.x));
        const float pp1 = __fsub_rn(p1, __fmul_rn(sh, ab.y));
        const float pp2 = __fsub_rn(p2, __fmul_rn(sh, ab.z));

        // onz = all_j (t_j < EPSV) == max_j t_j < EPSV  (broadcast LDS reads)
        float m0 = -INFINITY, m1 = -INFINITY;
        #pragma unroll
        for (int j = 0; j < H; j += 2) {
            const float4 qa = sAb[j];
            const float ta = __fsub_rn(
                __fadd_rn(__fadd_rn(__fmul_rn(pp0, qa.x), __fmul_rn(pp1, qa.y)),
                          __fmul_rn(pp2, qa.z)),
                qa.w);
            m0 = fmaxf(m0, ta);
            const float4 qb = sAb[j + 1];
            const float tb = __fsub_rn(
                __fadd_rn(__fadd_rn(__fmul_rn(pp0, qb.x), __fmul_rn(pp1, qb.y)),
                          __fmul_rn(pp2, qb.z)),
                qb.w);
            m1 = fmaxf(m1, tb);
        }
        const bool onz = (fmaxf(m0, m1) < EPSV);

        const float d0 = __fsub_rn(p0, pp0);
        const float d1 = __fsub_rn(p1, pp1);
        const float d2 = __fsub_rn(p2, pp2);
        float perp = __fsqrt_rn(
            __fadd_rn(__fadd_rn(__fmul_rn(d0, d0), __fmul_rn(d1, d1)),
                      __fmul_rn(d2, d2)));
        if (!onz) perp = INFINITY;
        if (perp < minperp) { minperp = perp; mini = h; }
    }

    // ---- edge pass over this slot's edges ----
    float mine = INFINITY; int midx = slot;
    float vm0 = 0.f, vm1 = 0.f, vm2 = 0.f;
    for (int v = slot; v < V; v += SLOTS) {
        const float4 V1 = sV1[v];
        const float4 E  = sE[v];
        const float w0 = __fsub_rn(p0, V1.x);
        const float w1 = __fsub_rn(p1, V1.y);
        const float w2 = __fsub_rn(p2, V1.z);
        const float th = __fdiv_rn(
            __fadd_rn(__fadd_rn(__fmul_rn(w0, E.x), __fmul_rn(w1, E.y)),
                      __fmul_rn(w2, E.z)),
            V1.w);
        const float ts = fminf(fmaxf(th, 0.f), 1.f);
        const float q0 = __fadd_rn(V1.x, __fmul_rn(ts, E.x));
        const float q1 = __fadd_rn(V1.y, __fmul_rn(ts, E.y));
        const float q2 = __fadd_rn(V1.z, __fmul_rn(ts, E.z));
        const float g0 = __fsub_rn(p0, q0);
        const float g1 = __fsub_rn(p1, q1);
        const float g2 = __fsub_rn(p2, q2);
        const float ed = __fsqrt_rn(
            __fadd_rn(__fadd_rn(__fmul_rn(g0, g0), __fmul_rn(g1, g1)),
                      __fmul_rn(g2, g2)));
        if (ed < mine) { mine = ed; midx = v; vm0 = q0; vm1 = q1; vm2 = q2; }
    }

    // ---- shfl-butterfly merge across the 4 slots (first-index tiebreak) ----
    unsigned negu = is_neg ? 1u : 0u;
    negu &= (unsigned)__shfl_xor((int)negu, 1);
    negu &= (unsigned)__shfl_xor((int)negu, 2);

    #pragma unroll
    for (int m = 1; m <= 2; m <<= 1) {
        const float ov = __shfl_xor(maxv, m);
        const int   oi = __shfl_xor(maxi, m);
        const bool take = (ov > maxv) || (ov == maxv && oi < maxi);
        maxv = take ? ov : maxv;  maxi = take ? oi : maxi;
    }
    #pragma unroll
    for (int m = 1; m <= 2; m <<= 1) {
        const float ov = __shfl_xor(minperp, m);
        const int   oi = __shfl_xor(mini, m);
        const bool take = (ov < minperp) || (ov == minperp && oi < mini);
        minperp = take ? ov : minperp;  mini = take ? oi : mini;
    }
    #pragma unroll
    for (int m = 1; m <= 2; m <<= 1) {
        const float ov  = __shfl_xor(mine, m);
        const int   oi  = __shfl_xor(midx, m);
        const float ov0 = __shfl_xor(vm0, m);
        const float ov1 = __shfl_xor(vm1, m);
        const float ov2 = __shfl_xor(vm2, m);
        const bool take = (ov < mine) || (ov == mine && oi < midx);
        mine = take ? ov : mine;  midx = take ? oi : midx;
        vm0 = take ? ov0 : vm0;  vm1 = take ? ov1 : vm1;  vm2 = take ? ov2 : vm2;
    }

    // ---- select (all 4 lanes agree; cooperative store) ----
    const bool  neg  = (negu != 0u);
    const int   fidx = neg ? maxi : mini;
    const float4 ga  = sAb[fidx];
    float dist = neg ? maxv : minperp;
    float g0 = ga.x, g1 = ga.y, g2 = ga.z;
    if (!neg && (mine < dist)) {
        dist = mine;
        g0 = __fdiv_rn(__fsub_rn(p0, vm0), mine);
        g1 = __fdiv_rn(__fsub_rn(p1, vm1), mine);
        g2 = __fdiv_rn(__fsub_rn(p2, vm2), mine);
    }

    const int idx = p * O + o;
    if (slot == 0)      dist_out[idx] = dist;
    else if (slot == 1) grad_out[idx * 3 + 0] = g0;
    else if (slot == 2) grad_out[idx * 3 + 1] = g1;
    else                grad_out[idx * 3 + 2] = g2;
}

extern "C" void kernel_launch(void* const* d_in, const int* in_sizes, int n_in,
                              void* d_out, int out_size, void* d_ws, size_t ws_size,
                              hipStream_t stream) {
    const float* point = (const float*)d_in[0];
    const float* hA    = (const float*)d_in[1];
    const float* hb    = (const float*)d_in[2];
    const float* v1    = (const float*)d_in[3];
    const float* v2    = (const float*)d_in[4];
    float* out = (float*)d_out;

    dim3 grid(P / PPB, O);
    zono_kernel<<<grid, dim3(256), 0, stream>>>(point, hA, hb, v1, v2,
                                                out, out + P * O);
}

// Round 5
// 29.239 us; speedup vs baseline: 3.1774x; 3.1774x over previous
//
#include <hip/hip_runtime.h>
#include <math.h>

namespace {
constexpr int P = 4096, O = 32, H = 26, V = 48;
constexpr float EPSV = 1e-4f;  // strict < EPSV == numpy's (f32 <= 1e-4 f64) exactly
}

// Process CNT consecutive faces (hq..hq+CNT-1) sharing each sAb[j] LDS read
// across the CNT projection tests. Arithmetic/order is bit-identical to the
// serial per-h version: numpy rounding (separate mul/add, sequential 3-term
// sums, IEEE sqrt), h-ascending updates, strict >/< first-index tiebreaks.
template<int CNT>
__device__ __forceinline__ void face_group(
    const float4* __restrict__ sAb, int hq,
    float p0, float p1, float p2,
    bool& is_neg, float& maxv, int& maxi, float& minperp, int& mini)
{
    float sh[CNT], pq0[CNT], pq1[CNT], pq2[CNT];
    #pragma unroll
    for (int u = 0; u < CNT; ++u) {
        const float4 ab = sAb[hq + u];
        sh[u] = __fsub_rn(
            __fadd_rn(__fadd_rn(__fmul_rn(p0, ab.x), __fmul_rn(p1, ab.y)),
                      __fmul_rn(p2, ab.z)),
            ab.w);
        pq0[u] = __fsub_rn(p0, __fmul_rn(sh[u], ab.x));
        pq1[u] = __fsub_rn(p1, __fmul_rn(sh[u], ab.y));
        pq2[u] = __fsub_rn(p2, __fmul_rn(sh[u], ab.z));
    }

    float m0[CNT], m1[CNT];
    #pragma unroll
    for (int u = 0; u < CNT; ++u) { m0[u] = -INFINITY; m1[u] = -INFINITY; }

    #pragma unroll
    for (int j = 0; j < H; j += 2) {           // H=26 even: 13 pairs
        const float4 qa = sAb[j];
        #pragma unroll
        for (int u = 0; u < CNT; ++u) {
            const float ta = __fsub_rn(
                __fadd_rn(__fadd_rn(__fmul_rn(pq0[u], qa.x), __fmul_rn(pq1[u], qa.y)),
                          __fmul_rn(pq2[u], qa.z)),
                qa.w);
            m0[u] = fmaxf(m0[u], ta);
        }
        const float4 qb = sAb[j + 1];
        #pragma unroll
        for (int u = 0; u < CNT; ++u) {
            const float tb = __fsub_rn(
                __fadd_rn(__fadd_rn(__fmul_rn(pq0[u], qb.x), __fmul_rn(pq1[u], qb.y)),
                          __fmul_rn(pq2[u], qb.z)),
                qb.w);
            m1[u] = fmaxf(m1[u], tb);
        }
    }

    #pragma unroll
    for (int u = 0; u < CNT; ++u) {            // updates in ascending-h order
        const int h = hq + u;
        if (sh[u] > 0.f) is_neg = false;
        if (sh[u] > maxv) { maxv = sh[u]; maxi = h; }   // first argmax

        const bool onz = (fmaxf(m0[u], m1[u]) < EPSV);

        const float d0 = __fsub_rn(p0, pq0[u]);
        const float d1 = __fsub_rn(p1, pq1[u]);
        const float d2 = __fsub_rn(p2, pq2[u]);
        float perp = __fsqrt_rn(
            __fadd_rn(__fadd_rn(__fmul_rn(d0, d0), __fmul_rn(d1, d1)),
                      __fmul_rn(d2, d2)));
        if (!onz) perp = INFINITY;
        if (perp < minperp) { minperp = perp; mini = h; } // first argmin
    }
}

__global__ __launch_bounds__(256, 2) void zono_kernel(
    const float* __restrict__ point,   // [P][3]
    const float* __restrict__ hA,      // [O][H][3]
    const float* __restrict__ hb,      // [O][H]
    const float* __restrict__ v1g,     // [O][V][3]
    const float* __restrict__ v2g,     // [O][V][3]
    float* __restrict__ dist_out,      // [P][O]
    float* __restrict__ grad_out)      // [P][O][3]
{
    __shared__ float4 sAb[H];   // {a0,a1,a2,b}
    __shared__ float4 sV1[V];   // {v1_0,v1_1,v1_2,denom}
    __shared__ float4 sE[V];    // {e0,e1,e2,unused}

    const int o   = blockIdx.y;
    const int tid = threadIdx.x;

    if (tid < H) {
        const float* a = hA + (o * H + tid) * 3;
        sAb[tid] = make_float4(a[0], a[1], a[2], hb[o * H + tid]);
    } else if (tid >= 32 && tid < 32 + V) {
        const int v = tid - 32;
        const float* A1 = v1g + (o * V + v) * 3;
        const float* A2 = v2g + (o * V + v) * 3;
        const float x0 = A1[0], x1 = A1[1], x2 = A1[2];
        const float e0 = __fsub_rn(A2[0], x0);
        const float e1 = __fsub_rn(A2[1], x1);
        const float e2 = __fsub_rn(A2[2], x2);
        const float den = __fadd_rn(__fadd_rn(__fmul_rn(e0, e0), __fmul_rn(e1, e1)),
                                    __fmul_rn(e2, e2));
        sV1[v] = make_float4(x0, x1, x2, den);
        sE[v]  = make_float4(e0, e1, e2, 0.f);
    }
    __syncthreads();

    const int p = blockIdx.x * blockDim.x + tid;
    const float p0 = point[p * 3 + 0];
    const float p1 = point[p * 3 + 1];
    const float p2 = point[p * 3 + 2];

    // ---- face pass: 6 quads + 1 pair (H = 26) ----
    bool  is_neg  = true;
    float maxv    = -INFINITY; int maxi = 0;
    float minperp =  INFINITY; int mini = 0;

    for (int hq = 0; hq < 24; hq += 4)
        face_group<4>(sAb, hq, p0, p1, p2, is_neg, maxv, maxi, minperp, mini);
    face_group<2>(sAb, 24, p0, p1, p2, is_neg, maxv, maxi, minperp, mini);

    // ---- edge pass: closest point on each segment ----
    float mine = INFINITY;
    float vm0 = 0.f, vm1 = 0.f, vm2 = 0.f;
    #pragma unroll 2
    for (int v = 0; v < V; ++v) {
        const float4 V1 = sV1[v];
        const float4 E  = sE[v];
        const float w0 = __fsub_rn(p0, V1.x);
        const float w1 = __fsub_rn(p1, V1.y);
        const float w2 = __fsub_rn(p2, V1.z);
        const float th = __fdiv_rn(
            __fadd_rn(__fadd_rn(__fmul_rn(w0, E.x), __fmul_rn(w1, E.y)),
                      __fmul_rn(w2, E.z)),
            V1.w);
        const float ts = fminf(fmaxf(th, 0.f), 1.f);
        const float q0 = __fadd_rn(V1.x, __fmul_rn(ts, E.x));
        const float q1 = __fadd_rn(V1.y, __fmul_rn(ts, E.y));
        const float q2 = __fadd_rn(V1.z, __fmul_rn(ts, E.z));
        const float g0 = __fsub_rn(p0, q0);
        const float g1 = __fsub_rn(p1, q1);
        const float g2 = __fsub_rn(p2, q2);
        const float ed = __fsqrt_rn(
            __fadd_rn(__fadd_rn(__fmul_rn(g0, g0), __fmul_rn(g1, g1)),
                      __fmul_rn(g2, g2)));
        if (ed < mine) { mine = ed; vm0 = q0; vm1 = q1; vm2 = q2; }
    }

    // ---- select ----
    const int   fidx = is_neg ? maxi : mini;
    const float4 ga  = sAb[fidx];   // dynamic index -> one LDS read
    float dist = is_neg ? maxv : minperp;
    float g0 = ga.x, g1 = ga.y, g2 = ga.z;
    if (!is_neg && (mine < dist)) {
        dist = mine;
        g0 = __fdiv_rn(__fsub_rn(p0, vm0), mine);
        g1 = __fdiv_rn(__fsub_rn(p1, vm1), mine);
        g2 = __fdiv_rn(__fsub_rn(p2, vm2), mine);
    }

    const int idx = p * O + o;
    dist_out[idx] = dist;
    grad_out[idx * 3 + 0] = g0;
    grad_out[idx * 3 + 1] = g1;
    grad_out[idx * 3 + 2] = g2;
}

extern "C" void kernel_launch(void* const* d_in, const int* in_sizes, int n_in,
                              void* d_out, int out_size, void* d_ws, size_t ws_size,
                              hipStream_t stream) {
    const float* point = (const float*)d_in[0];
    const float* hA    = (const float*)d_in[1];
    const float* hb    = (const float*)d_in[2];
    const float* v1    = (const float*)d_in[3];
    const float* v2    = (const float*)d_in[4];
    float* out = (float*)d_out;

    dim3 grid(P / 256, O);
    zono_kernel<<<grid, dim3(256), 0, stream>>>(point, hA, hb, v1, v2,
                                                out, out + P * O);
}